// Round 1
// baseline (673.681 us; speedup 1.0000x reference)
//
#include <hip/hip_runtime.h>
#include <cstdint>
#include <cstddef>

#define BN_EPSF 1e-5f

constexpr int B_  = 32, N_ = 512, F_ = 1024, E_ = 32768;
constexpr int H1_ = 512, H2_ = 256, H3_ = 128, NC_ = 8, EC_ = 10;
constexpr int M_  = B_ * N_;      // 16384 node rows
constexpr int NE_ = B_ * E_;      // 1048576 edges

// ---------------------------------------------------------------------------
// node_attr pack: [bbox/1024 (4), dir (4), pri (1), pad (3)] -> stride 12
// ---------------------------------------------------------------------------
__global__ __launch_bounds__(256) void k_node_attr(
    const float* __restrict__ bbox, const float* __restrict__ dir,
    const float* __restrict__ pri, float* __restrict__ na)
{
  int i = blockIdx.x * 256 + threadIdx.x;
  if (i >= M_) return;
  float4 b = *(const float4*)(bbox + (size_t)i * 4);
  float4 d = *(const float4*)(dir + (size_t)i * 4);
  float p = pri[i];
  const float inv = 1.0f / 1024.0f;
  float* o = na + (size_t)i * 12;
  *(float4*)(o + 0) = make_float4(b.x * inv, b.y * inv, b.z * inv, b.w * inv);
  *(float4*)(o + 4) = make_float4(d.x, d.y, d.z, d.w);
  *(float4*)(o + 8) = make_float4(p, 0.f, 0.f, 0.f);
}

// ---------------------------------------------------------------------------
// fp32 tiled GEMM, C = epi(A@W + bias). A: MxK row-major, W: KxN row-major.
// EPI 0: relu(bn(v)), EPI 1: relu(v).
// Tile 64x64, K-step 32, 256 threads, 4x4 per-thread microtile.
// ---------------------------------------------------------------------------
template <int EPI>
__global__ __launch_bounds__(256) void k_gemm_epi(
    const float* __restrict__ A, const float* __restrict__ W,
    const float* __restrict__ bias,
    const float* __restrict__ g, const float* __restrict__ bb,
    const float* __restrict__ rm, const float* __restrict__ rv,
    float* __restrict__ C, int M, int K, int N)
{
  __shared__ float As[32][68];   // transposed: As[k][m], pad 4 -> 272B rows
  __shared__ float Bs[32][68];   // Bs[k][n]

  const int tid = threadIdx.x;
  const int m0 = blockIdx.y * 64;
  const int n0 = blockIdx.x * 64;

  const int ar = tid >> 3;            // 0..31 (A row within tile, +32)
  const int ac = (tid & 7) * 4;       // 0..28 (A col4)
  const int br = tid >> 4;            // 0..15 (W row within k-tile, +16)
  const int bc = (tid & 15) * 4;      // 0..60 (W col4)
  const int tx = tid & 15;            // output col group
  const int ty = tid >> 4;            // output row group

  float acc[4][4] = {};

  for (int k0 = 0; k0 < K; k0 += 32) {
#pragma unroll
    for (int r = 0; r < 2; r++) {
      int row = ar + r * 32;
      float4 v = *(const float4*)&A[(size_t)(m0 + row) * K + k0 + ac];
      As[ac + 0][row] = v.x; As[ac + 1][row] = v.y;
      As[ac + 2][row] = v.z; As[ac + 3][row] = v.w;
    }
#pragma unroll
    for (int r = 0; r < 2; r++) {
      int row = br + r * 16;
      float4 v = *(const float4*)&W[(size_t)(k0 + row) * N + n0 + bc];
      *(float4*)&Bs[row][bc] = v;
    }
    __syncthreads();
#pragma unroll
    for (int k = 0; k < 32; k++) {
      float4 a = *(const float4*)&As[k][ty * 4];
      float4 b = *(const float4*)&Bs[k][tx * 4];
      float av[4] = {a.x, a.y, a.z, a.w};
      float bv[4] = {b.x, b.y, b.z, b.w};
#pragma unroll
      for (int i = 0; i < 4; i++)
#pragma unroll
        for (int j = 0; j < 4; j++)
          acc[i][j] = fmaf(av[i], bv[j], acc[i][j]);
    }
    __syncthreads();
  }

#pragma unroll
  for (int i = 0; i < 4; i++) {
    int m = m0 + ty * 4 + i;
    float4 o;
    float* po = (float*)&o;
#pragma unroll
    for (int j = 0; j < 4; j++) {
      int n = n0 + tx * 4 + j;
      float v = acc[i][j] + bias[n];
      if (EPI == 0) {
        float s = g[n] * rsqrtf(rv[n] + BN_EPSF);
        v = (v - rm[n]) * s + bb[n];
      }
      po[j] = fmaxf(v, 0.f);
    }
    *(float4*)&C[(size_t)m * N + n0 + tx * 4] = o;
  }
}

// ---------------------------------------------------------------------------
// node head: sigmoid(h3 @ ni_w + ni_b), K=128, N=8. One row per thread.
// ---------------------------------------------------------------------------
__global__ __launch_bounds__(256) void k_node_head(
    const float* __restrict__ h3, const float* __restrict__ w,
    const float* __restrict__ b, float* __restrict__ out)
{
  __shared__ __align__(16) float sw[H3_ * NC_];
  __shared__ float sb[NC_];
  for (int i = threadIdx.x; i < H3_ * NC_; i += 256) sw[i] = w[i];
  if (threadIdx.x < NC_) sb[threadIdx.x] = b[threadIdx.x];
  __syncthreads();

  int row = blockIdx.x * 256 + threadIdx.x;
  if (row >= M_) return;
  const float* hr = h3 + (size_t)row * H3_;
  float acc[NC_];
#pragma unroll
  for (int c = 0; c < NC_; c++) acc[c] = sb[c];
  for (int k = 0; k < H3_; k += 4) {
    float4 h = *(const float4*)&hr[k];
    float hv[4] = {h.x, h.y, h.z, h.w};
#pragma unroll
    for (int kk = 0; kk < 4; kk++)
#pragma unroll
      for (int c = 0; c < NC_; c++)
        acc[c] = fmaf(hv[kk], sw[(k + kk) * NC_ + c], acc[c]);
  }
  float4 o1, o2;
  float* p1 = (float*)&o1; float* p2 = (float*)&o2;
#pragma unroll
  for (int c = 0; c < 4; c++) {
    p1[c] = 1.f / (1.f + __expf(-acc[c]));
    p2[c] = 1.f / (1.f + __expf(-acc[c + 4]));
  }
  *(float4*)&out[(size_t)row * NC_ + 0] = o1;
  *(float4*)&out[(size_t)row * NC_ + 4] = o2;
}

// ---------------------------------------------------------------------------
// fused edge MLP: gather 2x9 attrs -> 18 -> 64 (relu) -> 64 (relu) -> 10 (sigmoid)
// All weights in LDS. h1 in registers (const-indexed via full unroll);
// layers 2+3 streamed in 8-wide chunks so h2 never materializes.
// ---------------------------------------------------------------------------
__global__ __launch_bounds__(256) void k_edge(
    const float* __restrict__ na, const int* __restrict__ eidx,
    const float* __restrict__ w1, const float* __restrict__ b1,
    const float* __restrict__ w2, const float* __restrict__ b2,
    const float* __restrict__ wo, const float* __restrict__ bo,
    float* __restrict__ out)
{
  __shared__ __align__(16) float sW1[18 * 64];
  __shared__ __align__(16) float sW2[64 * 64];
  __shared__ __align__(16) float sWo[64 * 10];
  __shared__ float sB1[64], sB2[64], sBo[10];

  const int tid = threadIdx.x;
  for (int i = tid; i < 18 * 64; i += 256) sW1[i] = w1[i];
  for (int i = tid; i < 64 * 64; i += 256) sW2[i] = w2[i];
  for (int i = tid; i < 64 * 10; i += 256) sWo[i] = wo[i];
  if (tid < 64) { sB1[tid] = b1[tid]; sB2[tid] = b2[tid]; }
  if (tid < 10) sBo[tid] = bo[tid];
  __syncthreads();

  const int e = blockIdx.x * 256 + tid;     // < NE_
  const int b = e >> 15;                    // E_ = 32768
  const int k = e & (E_ - 1);
  const int* ei = eidx + (size_t)b * 2 * E_;
  const int s = ei[k];
  const int d = ei[E_ + k];

  float x[18];
  {
    const float* ps = na + ((size_t)b * N_ + s) * 12;
    const float* pd = na + ((size_t)b * N_ + d) * 12;
    float4 a0 = *(const float4*)(ps + 0);
    float4 a1 = *(const float4*)(ps + 4);
    float4 a2 = *(const float4*)(ps + 8);
    float4 c0 = *(const float4*)(pd + 0);
    float4 c1 = *(const float4*)(pd + 4);
    float4 c2 = *(const float4*)(pd + 8);
    x[0] = a0.x; x[1] = a0.y; x[2] = a0.z; x[3] = a0.w;
    x[4] = a1.x; x[5] = a1.y; x[6] = a1.z; x[7] = a1.w;
    x[8] = a2.x;
    x[9]  = c0.x; x[10] = c0.y; x[11] = c0.z; x[12] = c0.w;
    x[13] = c1.x; x[14] = c1.y; x[15] = c1.z; x[16] = c1.w;
    x[17] = c2.x;
  }

  // layer 1: 18 -> 64, h1 in registers
  float h1[64];
#pragma unroll
  for (int j = 0; j < 16; j++) {
    float4 bv = *(const float4*)&sB1[j * 4];
    h1[j * 4 + 0] = bv.x; h1[j * 4 + 1] = bv.y;
    h1[j * 4 + 2] = bv.z; h1[j * 4 + 3] = bv.w;
  }
#pragma unroll
  for (int i = 0; i < 18; i++) {
    float xi = x[i];
#pragma unroll
    for (int j4 = 0; j4 < 16; j4++) {
      float4 w = *(const float4*)&sW1[i * 64 + j4 * 4];
      h1[j4 * 4 + 0] = fmaf(xi, w.x, h1[j4 * 4 + 0]);
      h1[j4 * 4 + 1] = fmaf(xi, w.y, h1[j4 * 4 + 1]);
      h1[j4 * 4 + 2] = fmaf(xi, w.z, h1[j4 * 4 + 2]);
      h1[j4 * 4 + 3] = fmaf(xi, w.w, h1[j4 * 4 + 3]);
    }
  }
#pragma unroll
  for (int j = 0; j < 64; j++) h1[j] = fmaxf(h1[j], 0.f);

  // layers 2+3 streamed: for each 8-chunk of h2, fold into out10
  float out10[10];
#pragma unroll
  for (int c = 0; c < 10; c++) out10[c] = sBo[c];

  for (int jo = 0; jo < 64; jo += 8) {     // rolled: LDS addrs dynamic, regs const-indexed
    float acc[8];
    float4 bva = *(const float4*)&sB2[jo];
    float4 bvb = *(const float4*)&sB2[jo + 4];
    acc[0] = bva.x; acc[1] = bva.y; acc[2] = bva.z; acc[3] = bva.w;
    acc[4] = bvb.x; acc[5] = bvb.y; acc[6] = bvb.z; acc[7] = bvb.w;
#pragma unroll
    for (int i = 0; i < 64; i++) {
      float hv = h1[i];
      float4 wa = *(const float4*)&sW2[i * 64 + jo];
      float4 wb = *(const float4*)&sW2[i * 64 + jo + 4];
      acc[0] = fmaf(hv, wa.x, acc[0]); acc[1] = fmaf(hv, wa.y, acc[1]);
      acc[2] = fmaf(hv, wa.z, acc[2]); acc[3] = fmaf(hv, wa.w, acc[3]);
      acc[4] = fmaf(hv, wb.x, acc[4]); acc[5] = fmaf(hv, wb.y, acc[5]);
      acc[6] = fmaf(hv, wb.z, acc[6]); acc[7] = fmaf(hv, wb.w, acc[7]);
    }
#pragma unroll
    for (int jj = 0; jj < 8; jj++) {
      float hv = fmaxf(acc[jj], 0.f);
      const float* wr = &sWo[(jo + jj) * 10];
#pragma unroll
      for (int c = 0; c < 10; c++) out10[c] = fmaf(hv, wr[c], out10[c]);
    }
  }

  float* op = out + (size_t)e * 10;
#pragma unroll
  for (int c = 0; c < 5; c++) {
    float2 v;
    v.x = 1.f / (1.f + __expf(-out10[c * 2 + 0]));
    v.y = 1.f / (1.f + __expf(-out10[c * 2 + 1]));
    *(float2*)(op + c * 2) = v;   // 8B-aligned: e*40 % 8 == 0
  }
}

// ---------------------------------------------------------------------------
extern "C" void kernel_launch(void* const* d_in, const int* in_sizes, int n_in,
                              void* d_out, int out_size, void* d_ws, size_t ws_size,
                              hipStream_t stream)
{
  const float* roi   = (const float*)d_in[0];
  const float* bbox  = (const float*)d_in[1];
  const float* dir   = (const float*)d_in[2];
  const float* pri   = (const float*)d_in[3];
  const int*   eidx  = (const int*)d_in[4];
  const float* w1    = (const float*)d_in[5];
  const float* b1    = (const float*)d_in[6];
  const float* g1    = (const float*)d_in[7];
  const float* bb1   = (const float*)d_in[8];
  const float* rm1   = (const float*)d_in[9];
  const float* rv1   = (const float*)d_in[10];
  const float* w2    = (const float*)d_in[11];
  const float* b2    = (const float*)d_in[12];
  const float* g2    = (const float*)d_in[13];
  const float* bb2   = (const float*)d_in[14];
  const float* rm2   = (const float*)d_in[15];
  const float* rv2   = (const float*)d_in[16];
  const float* w3    = (const float*)d_in[17];
  const float* b3    = (const float*)d_in[18];
  const float* niw   = (const float*)d_in[19];
  const float* nib   = (const float*)d_in[20];
  const float* ew1   = (const float*)d_in[21];
  const float* eb1   = (const float*)d_in[22];
  const float* ew2   = (const float*)d_in[23];
  const float* eb2   = (const float*)d_in[24];
  const float* eow   = (const float*)d_in[25];
  const float* eob   = (const float*)d_in[26];

  float* out_node = (float*)d_out;                   // 16384 x 8
  float* out_edge = (float*)d_out + (size_t)M_ * NC_; // 1048576 x 10

  float* h1 = (float*)d_ws;                          // 16384 x 512
  float* h2 = h1 + (size_t)M_ * H1_;                 // 16384 x 256
  float* h3 = h2 + (size_t)M_ * H2_;                 // 16384 x 128
  float* na = h3 + (size_t)M_ * H3_;                 // 16384 x 12

  k_node_attr<<<M_ / 256, 256, 0, stream>>>(bbox, dir, pri, na);

  k_edge<<<NE_ / 256, 256, 0, stream>>>(na, eidx, ew1, eb1, ew2, eb2, eow, eob,
                                        out_edge);

  k_gemm_epi<0><<<dim3(H1_ / 64, M_ / 64), 256, 0, stream>>>(
      roi, w1, b1, g1, bb1, rm1, rv1, h1, M_, F_, H1_);
  k_gemm_epi<0><<<dim3(H2_ / 64, M_ / 64), 256, 0, stream>>>(
      h1, w2, b2, g2, bb2, rm2, rv2, h2, M_, H1_, H2_);
  k_gemm_epi<1><<<dim3(H3_ / 64, M_ / 64), 256, 0, stream>>>(
      h2, w3, b3, nullptr, nullptr, nullptr, nullptr, h3, M_, H2_, H3_);

  k_node_head<<<M_ / 256, 256, 0, stream>>>(h3, niw, nib, out_node);
}

// Round 2
// 421.377 us; speedup vs baseline: 1.5988x; 1.5988x over previous
//
#include <hip/hip_runtime.h>
#include <cstdint>
#include <cstddef>

#define BN_EPSF 1e-5f

constexpr int B_  = 32, N_ = 512, F_ = 1024, E_ = 32768;
constexpr int H1_ = 512, H2_ = 256, H3_ = 128, NC_ = 8, EC_ = 10;
constexpr int M_  = B_ * N_;      // 16384 node rows
constexpr int NE_ = B_ * E_;      // 1048576 edges

typedef short bf16x8 __attribute__((ext_vector_type(8)));
typedef float f32x4  __attribute__((ext_vector_type(4)));

__device__ __forceinline__ short f2bf(float f) {
  union { float f; unsigned u; } v; v.f = f;
  unsigned r = v.u + 0x7fffu + ((v.u >> 16) & 1u);   // RNE
  return (short)(r >> 16);
}
__device__ __forceinline__ float bfbits(unsigned u) {
  union { unsigned u; float f; } v; v.u = u; return v.f;
}

// ---------------------------------------------------------------------------
// fp32 -> bf16 flat convert (8 elems/thread)
// ---------------------------------------------------------------------------
__global__ __launch_bounds__(256) void k_f2bf(
    const float* __restrict__ in, ushort* __restrict__ out, int n8)
{
  int i = blockIdx.x * 256 + threadIdx.x;
  if (i >= n8) return;
  float4 a = *(const float4*)(in + (size_t)i * 8);
  float4 b = *(const float4*)(in + (size_t)i * 8 + 4);
  ushort o[8];
  o[0] = (ushort)f2bf(a.x); o[1] = (ushort)f2bf(a.y);
  o[2] = (ushort)f2bf(a.z); o[3] = (ushort)f2bf(a.w);
  o[4] = (ushort)f2bf(b.x); o[5] = (ushort)f2bf(b.y);
  o[6] = (ushort)f2bf(b.z); o[7] = (ushort)f2bf(b.w);
  *(uint4*)(out + (size_t)i * 8) = *(uint4*)o;
}

// ---------------------------------------------------------------------------
// weight transpose+convert: W (KxN fp32, row-major) -> Wt (NxK bf16, row-major)
// ---------------------------------------------------------------------------
__global__ __launch_bounds__(256) void k_wt(
    const float* __restrict__ W, short* __restrict__ Wt, int K, int N)
{
  __shared__ float s[32][33];
  const int tx = threadIdx.x & 31, ty = threadIdx.x >> 5;  // ty 0..7
  const int k0 = blockIdx.y * 32, n0 = blockIdx.x * 32;
#pragma unroll
  for (int r = 0; r < 4; r++)
    s[ty * 4 + r][tx] = W[(size_t)(k0 + ty * 4 + r) * N + n0 + tx];
  __syncthreads();
#pragma unroll
  for (int r = 0; r < 4; r++)
    Wt[(size_t)(n0 + ty * 4 + r) * K + k0 + tx] = f2bf(s[tx][ty * 4 + r]);
}

// ---------------------------------------------------------------------------
// bf16 MFMA GEMM (m97 structure): C = epi(A@B + bias)
// A: MxK bf16 row-major. Wt: NxK bf16 row-major (pre-transposed weights).
// 128x128 tile, BK=32, 256 thr (4 waves, 2x2), 4x4 x mfma_16x16x32 per wave.
// EPI 0: relu(bn(v)); EPI 1: relu(v). Output bf16.
// ---------------------------------------------------------------------------
template <int EPI>
__global__ __launch_bounds__(256) void k_gemm_mfma(
    const short* __restrict__ A, const short* __restrict__ Wt,
    const float* __restrict__ bias,
    const float* __restrict__ g, const float* __restrict__ bb,
    const float* __restrict__ rm, const float* __restrict__ rv,
    short* __restrict__ C, int M, int K, int N)
{
  __shared__ short As[128 * 32];
  __shared__ short Bs[128 * 32];

  const int tid  = threadIdx.x;
  const int wave = tid >> 6, lane = tid & 63;
  const int m0 = blockIdx.y * 128, n0 = blockIdx.x * 128;
  const int wm = wave >> 1, wn = wave & 1;

  const int arow = tid >> 2;            // 0..63
  const int akq  = (tid & 3) * 8;       // k offset in elements

  f32x4 acc[4][4] = {};

  for (int k0 = 0; k0 < K; k0 += 32) {
#pragma unroll
    for (int it = 0; it < 2; it++) {
      const short* gp = A + (size_t)(m0 + it * 64 + arow) * K + k0 + akq;
      char* lp = (char*)As + it * 4096 + wave * 1024;   // + lane*16 by HW
      __builtin_amdgcn_global_load_lds(
          (const __attribute__((address_space(1))) void*)gp,
          (__attribute__((address_space(3))) void*)lp, 16, 0, 0);
    }
#pragma unroll
    for (int it = 0; it < 2; it++) {
      const short* gp = Wt + (size_t)(n0 + it * 64 + arow) * K + k0 + akq;
      char* lp = (char*)Bs + it * 4096 + wave * 1024;
      __builtin_amdgcn_global_load_lds(
          (const __attribute__((address_space(1))) void*)gp,
          (__attribute__((address_space(3))) void*)lp, 16, 0, 0);
    }
    __syncthreads();

    const int ko = (lane >> 4) * 8;
    bf16x8 af[4], bfr[4];
#pragma unroll
    for (int t = 0; t < 4; t++) {
      af[t]  = *(const bf16x8*)&As[(wm * 64 + t * 16 + (lane & 15)) * 32 + ko];
      bfr[t] = *(const bf16x8*)&Bs[(wn * 64 + t * 16 + (lane & 15)) * 32 + ko];
    }
#pragma unroll
    for (int ti = 0; ti < 4; ti++)
#pragma unroll
      for (int tj = 0; tj < 4; tj++)
        acc[ti][tj] = __builtin_amdgcn_mfma_f32_16x16x32_bf16(
            af[ti], bfr[tj], acc[ti][tj], 0, 0, 0);
    __syncthreads();
  }

  // epilogue: C/D layout col=lane&15, row=(lane>>4)*4+reg
#pragma unroll
  for (int tj = 0; tj < 4; tj++) {
    const int col = n0 + wn * 64 + tj * 16 + (lane & 15);
    const float bi = bias[col];
    float s = 1.f, t = 0.f;
    if (EPI == 0) {
      s = g[col] * rsqrtf(rv[col] + BN_EPSF);
      t = bb[col] - rm[col] * s;
    }
#pragma unroll
    for (int ti = 0; ti < 4; ti++) {
      const int rbase = m0 + wm * 64 + ti * 16 + ((lane >> 4) << 2);
#pragma unroll
      for (int r = 0; r < 4; r++) {
        float v = acc[ti][tj][r] + bi;
        if (EPI == 0) v = fmaf(v, s, t);
        v = fmaxf(v, 0.f);
        C[(size_t)(rbase + r) * N + col] = f2bf(v);
      }
    }
  }
}

// ---------------------------------------------------------------------------
// node_attr pack: [bbox/1024 (4), dir (4), pri (1), pad (3)] -> stride 12
// ---------------------------------------------------------------------------
__global__ __launch_bounds__(256) void k_node_attr(
    const float* __restrict__ bbox, const float* __restrict__ dir,
    const float* __restrict__ pri, float* __restrict__ na)
{
  int i = blockIdx.x * 256 + threadIdx.x;
  if (i >= M_) return;
  float4 b = *(const float4*)(bbox + (size_t)i * 4);
  float4 d = *(const float4*)(dir + (size_t)i * 4);
  float p = pri[i];
  const float inv = 1.0f / 1024.0f;
  float* o = na + (size_t)i * 12;
  *(float4*)(o + 0) = make_float4(b.x * inv, b.y * inv, b.z * inv, b.w * inv);
  *(float4*)(o + 4) = make_float4(d.x, d.y, d.z, d.w);
  *(float4*)(o + 8) = make_float4(p, 0.f, 0.f, 0.f);
}

// ---------------------------------------------------------------------------
// node head: sigmoid(h3 @ ni_w + ni_b), h3 bf16, K=128, N=8. One row/thread.
// ---------------------------------------------------------------------------
__global__ __launch_bounds__(256) void k_node_head(
    const ushort* __restrict__ h3, const float* __restrict__ w,
    const float* __restrict__ b, float* __restrict__ out)
{
  __shared__ __align__(16) float sw[H3_ * NC_];
  __shared__ float sb[NC_];
  for (int i = threadIdx.x; i < H3_ * NC_; i += 256) sw[i] = w[i];
  if (threadIdx.x < NC_) sb[threadIdx.x] = b[threadIdx.x];
  __syncthreads();

  int row = blockIdx.x * 256 + threadIdx.x;
  if (row >= M_) return;
  const ushort* hr = h3 + (size_t)row * H3_;
  float acc[NC_];
#pragma unroll
  for (int c = 0; c < NC_; c++) acc[c] = sb[c];
  for (int k = 0; k < H3_; k += 8) {
    uint4 u = *(const uint4*)&hr[k];
    float hv[8];
    hv[0] = bfbits(u.x << 16); hv[1] = bfbits(u.x & 0xffff0000u);
    hv[2] = bfbits(u.y << 16); hv[3] = bfbits(u.y & 0xffff0000u);
    hv[4] = bfbits(u.z << 16); hv[5] = bfbits(u.z & 0xffff0000u);
    hv[6] = bfbits(u.w << 16); hv[7] = bfbits(u.w & 0xffff0000u);
#pragma unroll
    for (int kk = 0; kk < 8; kk++)
#pragma unroll
      for (int c = 0; c < NC_; c++)
        acc[c] = fmaf(hv[kk], sw[(k + kk) * NC_ + c], acc[c]);
  }
  float4 o1, o2;
  float* p1 = (float*)&o1; float* p2 = (float*)&o2;
#pragma unroll
  for (int c = 0; c < 4; c++) {
    p1[c] = 1.f / (1.f + __expf(-acc[c]));
    p2[c] = 1.f / (1.f + __expf(-acc[c + 4]));
  }
  *(float4*)&out[(size_t)row * NC_ + 0] = o1;
  *(float4*)&out[(size_t)row * NC_ + 4] = o2;
}

// ---------------------------------------------------------------------------
// fused edge MLP: gather 2x9 attrs -> 18 -> 64 (relu) -> 64 (relu) -> 10 (sig)
// ---------------------------------------------------------------------------
__global__ __launch_bounds__(256) void k_edge(
    const float* __restrict__ na, const int* __restrict__ eidx,
    const float* __restrict__ w1, const float* __restrict__ b1,
    const float* __restrict__ w2, const float* __restrict__ b2,
    const float* __restrict__ wo, const float* __restrict__ bo,
    float* __restrict__ out)
{
  __shared__ __align__(16) float sW1[18 * 64];
  __shared__ __align__(16) float sW2[64 * 64];
  __shared__ __align__(16) float sWo[64 * 10];
  __shared__ float sB1[64], sB2[64], sBo[10];

  const int tid = threadIdx.x;
  for (int i = tid; i < 18 * 64; i += 256) sW1[i] = w1[i];
  for (int i = tid; i < 64 * 64; i += 256) sW2[i] = w2[i];
  for (int i = tid; i < 64 * 10; i += 256) sWo[i] = wo[i];
  if (tid < 64) { sB1[tid] = b1[tid]; sB2[tid] = b2[tid]; }
  if (tid < 10) sBo[tid] = bo[tid];
  __syncthreads();

  const int e = blockIdx.x * 256 + tid;
  const int b = e >> 15;                    // E_ = 32768
  const int k = e & (E_ - 1);
  const int* ei = eidx + (size_t)b * 2 * E_;
  const int s = ei[k];
  const int d = ei[E_ + k];

  float x[18];
  {
    const float* ps = na + ((size_t)b * N_ + s) * 12;
    const float* pd = na + ((size_t)b * N_ + d) * 12;
    float4 a0 = *(const float4*)(ps + 0);
    float4 a1 = *(const float4*)(ps + 4);
    float4 a2 = *(const float4*)(ps + 8);
    float4 c0 = *(const float4*)(pd + 0);
    float4 c1 = *(const float4*)(pd + 4);
    float4 c2 = *(const float4*)(pd + 8);
    x[0] = a0.x; x[1] = a0.y; x[2] = a0.z; x[3] = a0.w;
    x[4] = a1.x; x[5] = a1.y; x[6] = a1.z; x[7] = a1.w;
    x[8] = a2.x;
    x[9]  = c0.x; x[10] = c0.y; x[11] = c0.z; x[12] = c0.w;
    x[13] = c1.x; x[14] = c1.y; x[15] = c1.z; x[16] = c1.w;
    x[17] = c2.x;
  }

  float h1[64];
#pragma unroll
  for (int j = 0; j < 16; j++) {
    float4 bv = *(const float4*)&sB1[j * 4];
    h1[j * 4 + 0] = bv.x; h1[j * 4 + 1] = bv.y;
    h1[j * 4 + 2] = bv.z; h1[j * 4 + 3] = bv.w;
  }
#pragma unroll
  for (int i = 0; i < 18; i++) {
    float xi = x[i];
#pragma unroll
    for (int j4 = 0; j4 < 16; j4++) {
      float4 w = *(const float4*)&sW1[i * 64 + j4 * 4];
      h1[j4 * 4 + 0] = fmaf(xi, w.x, h1[j4 * 4 + 0]);
      h1[j4 * 4 + 1] = fmaf(xi, w.y, h1[j4 * 4 + 1]);
      h1[j4 * 4 + 2] = fmaf(xi, w.z, h1[j4 * 4 + 2]);
      h1[j4 * 4 + 3] = fmaf(xi, w.w, h1[j4 * 4 + 3]);
    }
  }
#pragma unroll
  for (int j = 0; j < 64; j++) h1[j] = fmaxf(h1[j], 0.f);

  float out10[10];
#pragma unroll
  for (int c = 0; c < 10; c++) out10[c] = sBo[c];

  for (int jo = 0; jo < 64; jo += 8) {
    float acc[8];
    float4 bva = *(const float4*)&sB2[jo];
    float4 bvb = *(const float4*)&sB2[jo + 4];
    acc[0] = bva.x; acc[1] = bva.y; acc[2] = bva.z; acc[3] = bva.w;
    acc[4] = bvb.x; acc[5] = bvb.y; acc[6] = bvb.z; acc[7] = bvb.w;
#pragma unroll
    for (int i = 0; i < 64; i++) {
      float hv = h1[i];
      float4 wa = *(const float4*)&sW2[i * 64 + jo];
      float4 wb = *(const float4*)&sW2[i * 64 + jo + 4];
      acc[0] = fmaf(hv, wa.x, acc[0]); acc[1] = fmaf(hv, wa.y, acc[1]);
      acc[2] = fmaf(hv, wa.z, acc[2]); acc[3] = fmaf(hv, wa.w, acc[3]);
      acc[4] = fmaf(hv, wb.x, acc[4]); acc[5] = fmaf(hv, wb.y, acc[5]);
      acc[6] = fmaf(hv, wb.z, acc[6]); acc[7] = fmaf(hv, wb.w, acc[7]);
    }
#pragma unroll
    for (int jj = 0; jj < 8; jj++) {
      float hv = fmaxf(acc[jj], 0.f);
      const float* wr = &sWo[(jo + jj) * 10];
#pragma unroll
      for (int c = 0; c < 10; c++) out10[c] = fmaf(hv, wr[c], out10[c]);
    }
  }

  float* op = out + (size_t)e * 10;
#pragma unroll
  for (int c = 0; c < 5; c++) {
    float2 v;
    v.x = 1.f / (1.f + __expf(-out10[c * 2 + 0]));
    v.y = 1.f / (1.f + __expf(-out10[c * 2 + 1]));
    *(float2*)(op + c * 2) = v;
  }
}

// ---------------------------------------------------------------------------
extern "C" void kernel_launch(void* const* d_in, const int* in_sizes, int n_in,
                              void* d_out, int out_size, void* d_ws, size_t ws_size,
                              hipStream_t stream)
{
  const float* roi   = (const float*)d_in[0];
  const float* bbox  = (const float*)d_in[1];
  const float* dir   = (const float*)d_in[2];
  const float* pri   = (const float*)d_in[3];
  const int*   eidx  = (const int*)d_in[4];
  const float* w1    = (const float*)d_in[5];
  const float* b1    = (const float*)d_in[6];
  const float* g1    = (const float*)d_in[7];
  const float* bb1   = (const float*)d_in[8];
  const float* rm1   = (const float*)d_in[9];
  const float* rv1   = (const float*)d_in[10];
  const float* w2    = (const float*)d_in[11];
  const float* b2    = (const float*)d_in[12];
  const float* g2    = (const float*)d_in[13];
  const float* bb2   = (const float*)d_in[14];
  const float* rm2   = (const float*)d_in[15];
  const float* rv2   = (const float*)d_in[16];
  const float* w3    = (const float*)d_in[17];
  const float* b3    = (const float*)d_in[18];
  const float* niw   = (const float*)d_in[19];
  const float* nib   = (const float*)d_in[20];
  const float* ew1   = (const float*)d_in[21];
  const float* eb1   = (const float*)d_in[22];
  const float* ew2   = (const float*)d_in[23];
  const float* eb2   = (const float*)d_in[24];
  const float* eow   = (const float*)d_in[25];
  const float* eob   = (const float*)d_in[26];

  float* out_node = (float*)d_out;                    // 16384 x 8
  float* out_edge = (float*)d_out + (size_t)M_ * NC_; // 1048576 x 10

  // workspace layout (bytes); h2/h3 overlay roiB (dead after L1 GEMM)
  char* w = (char*)d_ws;
  short*  roiB = (short*)w;                                   // 33,554,432
  short*  h2   = (short*)w;                                   // 8,388,608
  ushort* h3   = (ushort*)(w + 8388608);                      // 4,194,304
  short*  h1   = (short*)(w + 33554432);                      // 16,777,216
  short*  w1t  = (short*)(w + 33554432 + 16777216);           // 1,048,576
  short*  w2t  = (short*)(w + 33554432 + 16777216 + 1048576); //   262,144
  short*  w3t  = (short*)(w + 33554432 + 16777216 + 1310720); //    65,536
  float*  na   = (float*)(w + 33554432 + 16777216 + 1376256); //   786,432

  // edge path (independent of node MLP)
  k_node_attr<<<M_ / 256, 256, 0, stream>>>(bbox, dir, pri, na);
  k_edge<<<NE_ / 256, 256, 0, stream>>>(na, eidx, ew1, eb1, ew2, eb2, eow, eob,
                                        out_edge);

  // conversions
  k_f2bf<<<(M_ * F_ / 8) / 256, 256, 0, stream>>>(roi, (ushort*)roiB, M_ * F_ / 8);
  k_wt<<<dim3(H1_ / 32, F_ / 32), 256, 0, stream>>>(w1, w1t, F_, H1_);
  k_wt<<<dim3(H2_ / 32, H1_ / 32), 256, 0, stream>>>(w2, w2t, H1_, H2_);
  k_wt<<<dim3(H3_ / 32, H2_ / 32), 256, 0, stream>>>(w3, w3t, H2_, H3_);

  // node MLP (bf16 MFMA)
  k_gemm_mfma<0><<<dim3(H1_ / 128, M_ / 128), 256, 0, stream>>>(
      roiB, w1t, b1, g1, bb1, rm1, rv1, h1, M_, F_, H1_);
  k_gemm_mfma<0><<<dim3(H2_ / 128, M_ / 128), 256, 0, stream>>>(
      h1, w2t, b2, g2, bb2, rm2, rv2, h2, M_, H1_, H2_);
  k_gemm_mfma<1><<<dim3(H3_ / 128, M_ / 128), 256, 0, stream>>>(
      h2, w3t, b3, nullptr, nullptr, nullptr, nullptr, (short*)h3, M_, H1_ / 2, H3_);

  k_node_head<<<M_ / 256, 256, 0, stream>>>(h3, niw, nib, out_node);
}

// Round 3
// 284.981 us; speedup vs baseline: 2.3640x; 1.4786x over previous
//
#include <hip/hip_runtime.h>
#include <cstdint>
#include <cstddef>

#define BN_EPSF 1e-5f

constexpr int B_  = 32, N_ = 512, F_ = 1024, E_ = 32768;
constexpr int H1_ = 512, H2_ = 256, H3_ = 128, NC_ = 8, EC_ = 10;
constexpr int M_  = B_ * N_;      // 16384 node rows
constexpr int NE_ = B_ * E_;      // 1048576 edges

typedef short bf16x8 __attribute__((ext_vector_type(8)));
typedef float f32x4  __attribute__((ext_vector_type(4)));

__device__ __forceinline__ short f2bf(float f) {
  union { float f; unsigned u; } v; v.f = f;
  unsigned r = v.u + 0x7fffu + ((v.u >> 16) & 1u);   // RNE
  return (short)(r >> 16);
}
__device__ __forceinline__ float bfbits(unsigned u) {
  union { unsigned u; float f; } v; v.u = u; return v.f;
}

// ---------------------------------------------------------------------------
// fp32 -> bf16 flat convert (8 elems/thread)
// ---------------------------------------------------------------------------
__global__ __launch_bounds__(256) void k_f2bf(
    const float* __restrict__ in, ushort* __restrict__ out, int n8)
{
  int i = blockIdx.x * 256 + threadIdx.x;
  if (i >= n8) return;
  float4 a = *(const float4*)(in + (size_t)i * 8);
  float4 b = *(const float4*)(in + (size_t)i * 8 + 4);
  ushort o[8];
  o[0] = (ushort)f2bf(a.x); o[1] = (ushort)f2bf(a.y);
  o[2] = (ushort)f2bf(a.z); o[3] = (ushort)f2bf(a.w);
  o[4] = (ushort)f2bf(b.x); o[5] = (ushort)f2bf(b.y);
  o[6] = (ushort)f2bf(b.z); o[7] = (ushort)f2bf(b.w);
  *(uint4*)(out + (size_t)i * 8) = *(uint4*)o;
}

// ---------------------------------------------------------------------------
// weight transpose+convert: W (KxN fp32, row-major) -> Wt (NxK bf16, row-major)
// ---------------------------------------------------------------------------
__global__ __launch_bounds__(256) void k_wt(
    const float* __restrict__ W, short* __restrict__ Wt, int K, int N)
{
  __shared__ float s[32][33];
  const int tx = threadIdx.x & 31, ty = threadIdx.x >> 5;  // ty 0..7
  const int k0 = blockIdx.y * 32, n0 = blockIdx.x * 32;
#pragma unroll
  for (int r = 0; r < 4; r++)
    s[ty * 4 + r][tx] = W[(size_t)(k0 + ty * 4 + r) * N + n0 + tx];
  __syncthreads();
#pragma unroll
  for (int r = 0; r < 4; r++)
    Wt[(size_t)(n0 + ty * 4 + r) * K + k0 + tx] = f2bf(s[tx][ty * 4 + r]);
}

// ---------------------------------------------------------------------------
// bf16 MFMA GEMM (m97 structure): C = epi(A@B + bias)
// A: MxK bf16 row-major. Wt: NxK bf16 row-major (pre-transposed weights).
// 128x128 tile, BK=32, 256 thr (4 waves, 2x2), 4x4 x mfma_16x16x32 per wave.
// EPI 0: relu(bn(v)); EPI 1: relu(v). Output bf16.
// ---------------------------------------------------------------------------
template <int EPI>
__global__ __launch_bounds__(256) void k_gemm_mfma(
    const short* __restrict__ A, const short* __restrict__ Wt,
    const float* __restrict__ bias,
    const float* __restrict__ g, const float* __restrict__ bb,
    const float* __restrict__ rm, const float* __restrict__ rv,
    short* __restrict__ C, int M, int K, int N)
{
  __shared__ short As[128 * 32];
  __shared__ short Bs[128 * 32];

  const int tid  = threadIdx.x;
  const int wave = tid >> 6, lane = tid & 63;
  const int m0 = blockIdx.y * 128, n0 = blockIdx.x * 128;
  const int wm = wave >> 1, wn = wave & 1;

  const int arow = tid >> 2;            // 0..63
  const int akq  = (tid & 3) * 8;       // k offset in elements

  f32x4 acc[4][4] = {};

  for (int k0 = 0; k0 < K; k0 += 32) {
#pragma unroll
    for (int it = 0; it < 2; it++) {
      const short* gp = A + (size_t)(m0 + it * 64 + arow) * K + k0 + akq;
      char* lp = (char*)As + it * 4096 + wave * 1024;   // + lane*16 by HW
      __builtin_amdgcn_global_load_lds(
          (const __attribute__((address_space(1))) void*)gp,
          (__attribute__((address_space(3))) void*)lp, 16, 0, 0);
    }
#pragma unroll
    for (int it = 0; it < 2; it++) {
      const short* gp = Wt + (size_t)(n0 + it * 64 + arow) * K + k0 + akq;
      char* lp = (char*)Bs + it * 4096 + wave * 1024;
      __builtin_amdgcn_global_load_lds(
          (const __attribute__((address_space(1))) void*)gp,
          (__attribute__((address_space(3))) void*)lp, 16, 0, 0);
    }
    __syncthreads();

    const int ko = (lane >> 4) * 8;
    bf16x8 af[4], bfr[4];
#pragma unroll
    for (int t = 0; t < 4; t++) {
      af[t]  = *(const bf16x8*)&As[(wm * 64 + t * 16 + (lane & 15)) * 32 + ko];
      bfr[t] = *(const bf16x8*)&Bs[(wn * 64 + t * 16 + (lane & 15)) * 32 + ko];
    }
#pragma unroll
    for (int ti = 0; ti < 4; ti++)
#pragma unroll
      for (int tj = 0; tj < 4; tj++)
        acc[ti][tj] = __builtin_amdgcn_mfma_f32_16x16x32_bf16(
            af[ti], bfr[tj], acc[ti][tj], 0, 0, 0);
    __syncthreads();
  }

  // epilogue: C/D layout col=lane&15, row=(lane>>4)*4+reg
#pragma unroll
  for (int tj = 0; tj < 4; tj++) {
    const int col = n0 + wn * 64 + tj * 16 + (lane & 15);
    const float bi = bias[col];
    float s = 1.f, t = 0.f;
    if (EPI == 0) {
      s = g[col] * rsqrtf(rv[col] + BN_EPSF);
      t = bb[col] - rm[col] * s;
    }
#pragma unroll
    for (int ti = 0; ti < 4; ti++) {
      const int rbase = m0 + wm * 64 + ti * 16 + ((lane >> 4) << 2);
#pragma unroll
      for (int r = 0; r < 4; r++) {
        float v = acc[ti][tj][r] + bi;
        if (EPI == 0) v = fmaf(v, s, t);
        v = fmaxf(v, 0.f);
        C[(size_t)(rbase + r) * N + col] = f2bf(v);
      }
    }
  }
}

// ---------------------------------------------------------------------------
// node_attr pack: [bbox/1024 (4), dir (4), pri (1), pad (3)] -> stride 12
// ---------------------------------------------------------------------------
__global__ __launch_bounds__(256) void k_node_attr(
    const float* __restrict__ bbox, const float* __restrict__ dir,
    const float* __restrict__ pri, float* __restrict__ na)
{
  int i = blockIdx.x * 256 + threadIdx.x;
  if (i >= M_) return;
  float4 b = *(const float4*)(bbox + (size_t)i * 4);
  float4 d = *(const float4*)(dir + (size_t)i * 4);
  float p = pri[i];
  const float inv = 1.0f / 1024.0f;
  float* o = na + (size_t)i * 12;
  *(float4*)(o + 0) = make_float4(b.x * inv, b.y * inv, b.z * inv, b.w * inv);
  *(float4*)(o + 4) = make_float4(d.x, d.y, d.z, d.w);
  *(float4*)(o + 8) = make_float4(p, 0.f, 0.f, 0.f);
}

// ---------------------------------------------------------------------------
// node head: sigmoid(h3 @ ni_w + ni_b), h3 bf16, K=128, N=8. One row/thread.
// ---------------------------------------------------------------------------
__global__ __launch_bounds__(256) void k_node_head(
    const ushort* __restrict__ h3, const float* __restrict__ w,
    const float* __restrict__ b, float* __restrict__ out)
{
  __shared__ __align__(16) float sw[H3_ * NC_];
  __shared__ float sb[NC_];
  for (int i = threadIdx.x; i < H3_ * NC_; i += 256) sw[i] = w[i];
  if (threadIdx.x < NC_) sb[threadIdx.x] = b[threadIdx.x];
  __syncthreads();

  int row = blockIdx.x * 256 + threadIdx.x;
  if (row >= M_) return;
  const ushort* hr = h3 + (size_t)row * H3_;
  float acc[NC_];
#pragma unroll
  for (int c = 0; c < NC_; c++) acc[c] = sb[c];
  for (int k = 0; k < H3_; k += 8) {
    uint4 u = *(const uint4*)&hr[k];
    float hv[8];
    hv[0] = bfbits(u.x << 16); hv[1] = bfbits(u.x & 0xffff0000u);
    hv[2] = bfbits(u.y << 16); hv[3] = bfbits(u.y & 0xffff0000u);
    hv[4] = bfbits(u.z << 16); hv[5] = bfbits(u.z & 0xffff0000u);
    hv[6] = bfbits(u.w << 16); hv[7] = bfbits(u.w & 0xffff0000u);
#pragma unroll
    for (int kk = 0; kk < 8; kk++)
#pragma unroll
      for (int c = 0; c < NC_; c++)
        acc[c] = fmaf(hv[kk], sw[(k + kk) * NC_ + c], acc[c]);
  }
  float4 o1, o2;
  float* p1 = (float*)&o1; float* p2 = (float*)&o2;
#pragma unroll
  for (int c = 0; c < 4; c++) {
    p1[c] = 1.f / (1.f + __expf(-acc[c]));
    p2[c] = 1.f / (1.f + __expf(-acc[c + 4]));
  }
  *(float4*)&out[(size_t)row * NC_ + 0] = o1;
  *(float4*)&out[(size_t)row * NC_ + 4] = o2;
}

// ---------------------------------------------------------------------------
// MFMA edge MLP: gather 2x9 attrs (bf16) -> 18 -> 64 relu -> 64 relu -> 10 sig
// 1024 blocks x 8 batches x 128 edges. All B-fragments (W1/W2/W3, NxK,
// zero-padded) live in VGPRs for the whole kernel. Layer outputs round-trip
// through LDS to convert MFMA C-layout -> A-layout. W-stage/X/H2 share one
// LDS region (live ranges disjoint, barrier-separated).
// ---------------------------------------------------------------------------
__global__ __launch_bounds__(256, 2) void k_edge_mfma(
    const float* __restrict__ na, const int* __restrict__ eidx,
    const float* __restrict__ w1, const float* __restrict__ b1,
    const float* __restrict__ w2, const float* __restrict__ b2,
    const float* __restrict__ wo, const float* __restrict__ bo,
    float* __restrict__ out)
{
  __shared__ __align__(16) short sA[9216];      // W-stage(7168) / X(128x40) / H2(128x72)
  __shared__ __align__(16) short sH1[128 * 72]; // 18 KB
  __shared__ float sB[144];                     // b1[64] b2[64] bo[16]

  const int tid  = threadIdx.x;
  const int wave = tid >> 6, lane = tid & 63;
  const int lm  = lane & 15;            // col within 16-tile
  const int lk8 = (lane >> 4) * 8;      // k offset within 32-chunk
  const int lr  = (lane >> 4) * 4;      // C-layout row base

  short* sW1 = sA;            // 64 x 32
  short* sW2 = sA + 2048;     // 64 x 64
  short* sW3 = sA + 6144;     // 16 x 64 (rows 10..15 zero)
  short* sX  = sA;            // 128 x 40 (k pad 18->32, +8 row pad)
  short* sH2 = sA;            // 128 x 72

  // ---- stage weights (once per block) ----
  for (int i = tid; i < 2048; i += 256) {
    int n = i >> 5, k = i & 31;
    sW1[i] = (k < 18) ? f2bf(w1[k * 64 + n]) : (short)0;
  }
  for (int i = tid; i < 4096; i += 256) {
    int n = i >> 6, k = i & 63;
    sW2[i] = f2bf(w2[k * 64 + n]);
  }
  for (int i = tid; i < 1024; i += 256) {
    int n = i >> 6, k = i & 63;
    sW3[i] = (n < 10) ? f2bf(wo[k * 10 + n]) : (short)0;
  }
  if (tid < 64) { sB[tid] = b1[tid]; sB[64 + tid] = b2[tid]; }
  if (tid < 16) sB[128 + tid] = (tid < 10) ? bo[tid] : 0.f;
  __syncthreads();

  // ---- B-fragments + biases into registers ----
  bf16x8 fW1[4], fW2[4][2], fW3[2];
#pragma unroll
  for (int t = 0; t < 4; t++)
    fW1[t] = *(const bf16x8*)&sW1[(t * 16 + lm) * 32 + lk8];
#pragma unroll
  for (int t = 0; t < 4; t++)
#pragma unroll
    for (int ks = 0; ks < 2; ks++)
      fW2[t][ks] = *(const bf16x8*)&sW2[(t * 16 + lm) * 64 + ks * 32 + lk8];
#pragma unroll
  for (int ks = 0; ks < 2; ks++)
    fW3[ks] = *(const bf16x8*)&sW3[lm * 64 + ks * 32 + lk8];
  float bias1v[4], bias2v[4];
#pragma unroll
  for (int t = 0; t < 4; t++) {
    bias1v[t] = sB[t * 16 + lm];
    bias2v[t] = sB[64 + t * 16 + lm];
  }
  const float biasOv = sB[128 + lm];
  __syncthreads();   // W-stage region dead; safe to reuse as X

  for (int bi = 0; bi < 8; bi++) {
    const int e0 = (blockIdx.x * 8 + bi) * 128;

    // ---- gather 128 edges -> X (bf16 A-layout rows) ----
    if (tid < 128) {
      int e = e0 + tid;
      int b = e >> 15, kk = e & (E_ - 1);
      const int* ei = eidx + (size_t)b * 2 * E_;
      int s = ei[kk], d = ei[E_ + kk];
      const float* ps = na + ((size_t)b * N_ + s) * 12;
      const float* pd = na + ((size_t)b * N_ + d) * 12;
      float4 a0 = *(const float4*)(ps);
      float4 a1 = *(const float4*)(ps + 4);
      float  a2 = ps[8];
      float4 c0 = *(const float4*)(pd);
      float4 c1 = *(const float4*)(pd + 4);
      float  c2 = pd[8];
      ushort xr[32];
      xr[0] = (ushort)f2bf(a0.x); xr[1] = (ushort)f2bf(a0.y);
      xr[2] = (ushort)f2bf(a0.z); xr[3] = (ushort)f2bf(a0.w);
      xr[4] = (ushort)f2bf(a1.x); xr[5] = (ushort)f2bf(a1.y);
      xr[6] = (ushort)f2bf(a1.z); xr[7] = (ushort)f2bf(a1.w);
      xr[8] = (ushort)f2bf(a2);
      xr[9]  = (ushort)f2bf(c0.x); xr[10] = (ushort)f2bf(c0.y);
      xr[11] = (ushort)f2bf(c0.z); xr[12] = (ushort)f2bf(c0.w);
      xr[13] = (ushort)f2bf(c1.x); xr[14] = (ushort)f2bf(c1.y);
      xr[15] = (ushort)f2bf(c1.z); xr[16] = (ushort)f2bf(c1.w);
      xr[17] = (ushort)f2bf(c2);
#pragma unroll
      for (int i = 18; i < 32; i++) xr[i] = 0;
      ushort* row = (ushort*)&sX[tid * 40];
      *(uint4*)(row + 0)  = *(uint4*)&xr[0];
      *(uint4*)(row + 8)  = *(uint4*)&xr[8];
      *(uint4*)(row + 16) = *(uint4*)&xr[16];
      *(uint4*)(row + 24) = *(uint4*)&xr[24];
    }
    __syncthreads();

    // ---- layer 1: X(128x32) @ W1 -> H1 (64 wide) ----
    bf16x8 a1f[2];
#pragma unroll
    for (int ti = 0; ti < 2; ti++)
      a1f[ti] = *(const bf16x8*)&sX[(wave * 32 + ti * 16 + lm) * 40 + lk8];
    f32x4 acc1[2][4] = {};
#pragma unroll
    for (int ti = 0; ti < 2; ti++)
#pragma unroll
      for (int tj = 0; tj < 4; tj++)
        acc1[ti][tj] = __builtin_amdgcn_mfma_f32_16x16x32_bf16(
            a1f[ti], fW1[tj], acc1[ti][tj], 0, 0, 0);
#pragma unroll
    for (int ti = 0; ti < 2; ti++)
#pragma unroll
      for (int tj = 0; tj < 4; tj++)
#pragma unroll
        for (int r = 0; r < 4; r++) {
          int row = wave * 32 + ti * 16 + lr + r;
          float v = acc1[ti][tj][r] + bias1v[tj];
          sH1[row * 72 + tj * 16 + lm] = f2bf(fmaxf(v, 0.f));
        }
    __syncthreads();   // all X reads done -> region A reusable as H2

    // ---- layer 2: H1(128x64) @ W2 -> H2 (64 wide) ----
    bf16x8 a2f[2][2];
#pragma unroll
    for (int ti = 0; ti < 2; ti++)
#pragma unroll
      for (int ks = 0; ks < 2; ks++)
        a2f[ti][ks] = *(const bf16x8*)&sH1[(wave * 32 + ti * 16 + lm) * 72 + ks * 32 + lk8];
    f32x4 acc2[2][4] = {};
#pragma unroll
    for (int ks = 0; ks < 2; ks++)
#pragma unroll
      for (int ti = 0; ti < 2; ti++)
#pragma unroll
        for (int tj = 0; tj < 4; tj++)
          acc2[ti][tj] = __builtin_amdgcn_mfma_f32_16x16x32_bf16(
              a2f[ti][ks], fW2[tj][ks], acc2[ti][tj], 0, 0, 0);
#pragma unroll
    for (int ti = 0; ti < 2; ti++)
#pragma unroll
      for (int tj = 0; tj < 4; tj++)
#pragma unroll
        for (int r = 0; r < 4; r++) {
          int row = wave * 32 + ti * 16 + lr + r;
          float v = acc2[ti][tj][r] + bias2v[tj];
          sH2[row * 72 + tj * 16 + lm] = f2bf(fmaxf(v, 0.f));
        }
    // H2 write->read is within-wave (each wave owns its 32 rows): no barrier

    // ---- layer 3: H2(128x64) @ W3 -> out (10 wide) ----
    bf16x8 a3f[2][2];
#pragma unroll
    for (int ti = 0; ti < 2; ti++)
#pragma unroll
      for (int ks = 0; ks < 2; ks++)
        a3f[ti][ks] = *(const bf16x8*)&sH2[(wave * 32 + ti * 16 + lm) * 72 + ks * 32 + lk8];
    f32x4 acc3[2] = {};
#pragma unroll
    for (int ks = 0; ks < 2; ks++)
#pragma unroll
      for (int ti = 0; ti < 2; ti++)
        acc3[ti] = __builtin_amdgcn_mfma_f32_16x16x32_bf16(
            a3f[ti][ks], fW3[ks], acc3[ti], 0, 0, 0);
    if (lm < 10) {
#pragma unroll
      for (int ti = 0; ti < 2; ti++)
#pragma unroll
        for (int r = 0; r < 4; r++) {
          int row = wave * 32 + ti * 16 + lr + r;
          float v = acc3[ti][r] + biasOv;
          out[(size_t)(e0 + row) * 10 + lm] = 1.f / (1.f + __expf(-v));
        }
    }
    __syncthreads();   // protect region A (H2 reads) from next batch's gather
  }
}

// ---------------------------------------------------------------------------
extern "C" void kernel_launch(void* const* d_in, const int* in_sizes, int n_in,
                              void* d_out, int out_size, void* d_ws, size_t ws_size,
                              hipStream_t stream)
{
  const float* roi   = (const float*)d_in[0];
  const float* bbox  = (const float*)d_in[1];
  const float* dir   = (const float*)d_in[2];
  const float* pri   = (const float*)d_in[3];
  const int*   eidx  = (const int*)d_in[4];
  const float* w1    = (const float*)d_in[5];
  const float* b1    = (const float*)d_in[6];
  const float* g1    = (const float*)d_in[7];
  const float* bb1   = (const float*)d_in[8];
  const float* rm1   = (const float*)d_in[9];
  const float* rv1   = (const float*)d_in[10];
  const float* w2    = (const float*)d_in[11];
  const float* b2    = (const float*)d_in[12];
  const float* g2    = (const float*)d_in[13];
  const float* bb2   = (const float*)d_in[14];
  const float* rm2   = (const float*)d_in[15];
  const float* rv2   = (const float*)d_in[16];
  const float* w3    = (const float*)d_in[17];
  const float* b3    = (const float*)d_in[18];
  const float* niw   = (const float*)d_in[19];
  const float* nib   = (const float*)d_in[20];
  const float* ew1   = (const float*)d_in[21];
  const float* eb1   = (const float*)d_in[22];
  const float* ew2   = (const float*)d_in[23];
  const float* eb2   = (const float*)d_in[24];
  const float* eow   = (const float*)d_in[25];
  const float* eob   = (const float*)d_in[26];

  float* out_node = (float*)d_out;                    // 16384 x 8
  float* out_edge = (float*)d_out + (size_t)M_ * NC_; // 1048576 x 10

  // workspace layout (bytes); h2/h3 overlay roiB (dead after L1 GEMM)
  char* w = (char*)d_ws;
  short*  roiB = (short*)w;                                   // 33,554,432
  short*  h2   = (short*)w;                                   // 8,388,608
  ushort* h3   = (ushort*)(w + 8388608);                      // 4,194,304
  short*  h1   = (short*)(w + 33554432);                      // 16,777,216
  short*  w1t  = (short*)(w + 33554432 + 16777216);           // 1,048,576
  short*  w2t  = (short*)(w + 33554432 + 16777216 + 1048576); //   262,144
  short*  w3t  = (short*)(w + 33554432 + 16777216 + 1310720); //    65,536
  float*  na   = (float*)(w + 33554432 + 16777216 + 1376256); //   786,432

  // edge path (independent of node MLP)
  k_node_attr<<<M_ / 256, 256, 0, stream>>>(bbox, dir, pri, na);
  k_edge_mfma<<<NE_ / (8 * 128), 256, 0, stream>>>(
      na, eidx, ew1, eb1, ew2, eb2, eow, eob, out_edge);

  // conversions
  k_f2bf<<<(M_ * F_ / 8) / 256, 256, 0, stream>>>(roi, (ushort*)roiB, M_ * F_ / 8);
  k_wt<<<dim3(H1_ / 32, F_ / 32), 256, 0, stream>>>(w1, w1t, F_, H1_);
  k_wt<<<dim3(H2_ / 32, H1_ / 32), 256, 0, stream>>>(w2, w2t, H1_, H2_);
  k_wt<<<dim3(H3_ / 32, H2_ / 32), 256, 0, stream>>>(w3, w3t, H2_, H3_);

  // node MLP (bf16 MFMA)
  k_gemm_mfma<0><<<dim3(H1_ / 128, M_ / 128), 256, 0, stream>>>(
      roiB, w1t, b1, g1, bb1, rm1, rv1, h1, M_, F_, H1_);
  k_gemm_mfma<0><<<dim3(H2_ / 128, M_ / 128), 256, 0, stream>>>(
      h1, w2t, b2, g2, bb2, rm2, rv2, h2, M_, H1_, H2_);
  k_gemm_mfma<1><<<dim3(H3_ / 128, M_ / 128), 256, 0, stream>>>(
      h2, w3t, b3, nullptr, nullptr, nullptr, nullptr, (short*)h3, M_, H1_ / 2, H3_);

  k_node_head<<<M_ / 256, 256, 0, stream>>>(h3, niw, nib, out_node);
}